// Round 4
// baseline (1945.882 us; speedup 1.0000x reference)
//
#include <hip/hip_runtime.h>
#include <hip/hip_bf16.h>
#include <stdint.h>

// BConv2d: out = conv2d(sign(x), sign(w), pad=1) + b
// N=32, Cin=256, H=W=56, Cout=256, K=3. fp32 in/out.
//
// dot(±1,±1) over 256-bit tap = 256 - 2*popcount(xor). OOB taps packed as
// all-zero bits (== all -1); false contribution removed via per-(border,co)
// table adj[bt][co] = bias[co] - sum_invalid(256 - 2*pop(w_tap)).
//
// R3 lesson: streaming 72 uniform weight dwords/co through the scalar path
// (SGPR budget 64) is the stall. R4: lane=co -> each lane PINS its co's 72
// packed weight words in VGPRs for the whole block; x taps broadcast from
// LDS (uniform ds_read_b128, conflict-free); stores scattered but
// write-combined in L2 (each wave fully covers its co-row lines).

#define NBATCH 32
#define CIN    256
#define COUT   256
#define HH     56
#define WW     56
#define HW     (HH*WW)          // 3136
#define NPIX   (NBATCH*HW)      // 100352

#define XP_BYTES ((size_t)NPIX * 8 * 4)        // 3,211,264
#define WP_BYTES ((size_t)COUT * 72 * 4)       // 73,728

// ---- pack x: wave handles 64 channels (2 words) for 64 pixels (lane=pixel)
__global__ __launch_bounds__(256) void pack_x_kernel(
    const float* __restrict__ x, uint32_t* __restrict__ xp)
{
    int lane = threadIdx.x & 63;
    int wv   = threadIdx.x >> 6;               // 0..3 -> channel group
    int pix  = blockIdx.x * 64 + lane;         // 1568 blocks * 64 == NPIX
    int n  = pix / HW;
    int hw = pix - n * HW;
    const float* xb = x + ((size_t)n * CIN + (size_t)wv * 64) * HW + hw;

    uint32_t w0 = 0, w1 = 0;
    #pragma unroll
    for (int j = 0; j < 32; ++j) {
        w0 |= (xb[(size_t)j * HW]        >= 0.0f ? 1u : 0u) << j;
        w1 |= (xb[(size_t)(j + 32) * HW] >= 0.0f ? 1u : 0u) << j;
    }
    *(uint2*)(xp + (size_t)pix * 8 + wv * 2) = make_uint2(w0, w1);
}

// ---- pack w (TRANSPOSED): wp_t[k*COUT + co], k = t*8 + wd
__global__ __launch_bounds__(256) void pack_w_kernel(
    const float* __restrict__ w, const float* __restrict__ bias,
    uint32_t* __restrict__ wp_t, float* __restrict__ adj)
{
    int co   = blockIdx.x;
    int ci   = threadIdx.x;                    // 0..255
    int lane = ci & 63, wv = ci >> 6;
    const float* wb = w + ((size_t)co * CIN + ci) * 9;

    float v[9];
    #pragma unroll
    for (int t = 0; t < 9; ++t) v[t] = wb[t];

    __shared__ int pops[4][9];
    __shared__ int popv[9];

    #pragma unroll
    for (int t = 0; t < 9; ++t) {
        unsigned long long m = __ballot(v[t] >= 0.0f);
        if (lane == 0) {
            wp_t[(size_t)(t * 8 + 2 * wv)     * COUT + co] = (uint32_t)m;
            wp_t[(size_t)(t * 8 + 2 * wv + 1) * COUT + co] = (uint32_t)(m >> 32);
            pops[wv][t] = (int)__popcll(m);
        }
    }
    __syncthreads();
    if (ci < 9) popv[ci] = pops[0][ci] + pops[1][ci] + pops[2][ci] + pops[3][ci];
    __syncthreads();
    if (ci < 9) {
        int bt = ci, ht = bt / 3, wt = bt % 3;
        float c = 0.0f;
        #pragma unroll
        for (int t = 0; t < 9; ++t) {
            int dh = t / 3, dw = t % 3;
            bool inv = (ht == 0 && dh == 0) || (ht == 2 && dh == 2) ||
                       (wt == 0 && dw == 0) || (wt == 2 && dw == 2);
            if (inv) c += (float)(CIN - 2 * popv[t]);
        }
        adj[bt * COUT + co] = bias[co] - c;
    }
}

// ---- conv: block = (n, h); wave g owns co-group g*64 + lane
__global__ __launch_bounds__(256, 3) void bconv_kernel(
    const uint32_t* __restrict__ xp, const uint32_t* __restrict__ wp_t,
    const float* __restrict__ adj, float* __restrict__ out)
{
    __shared__ __align__(16) uint32_t tile[3][58][8];   // 5568 B, zero-padded cols

    int bx = blockIdx.x;                // 0..1791
    int n  = bx / HH;
    int h  = bx - n * HH;
    int tid  = threadIdx.x;
    int lane = tid & 63;
    int wg   = tid >> 6;
    int co   = wg * 64 + lane;

    // stage x rows h-1..h+1 (zero rows/cols at borders), coalesced uint2
    for (int e = tid; e < 3 * 58 * 4; e += 256) {
        int r   = e / (58 * 4);
        int rem = e - r * (58 * 4);
        int c   = rem >> 2;
        int j   = rem & 3;
        int hh2 = h + r - 1, ww2 = c - 1;
        uint2 v = make_uint2(0u, 0u);
        if ((unsigned)hh2 < HH && (unsigned)ww2 < WW)
            v = *(const uint2*)(xp + ((size_t)n * HW + hh2 * WW + ww2) * 8 + 2 * j);
        *(uint2*)(&tile[r][c][2 * j]) = v;
    }

    // pin this lane's co weights in VGPRs (coalesced loads, L2-resident)
    uint32_t wreg[72];
    #pragma unroll
    for (int k = 0; k < 72; ++k) wreg[k] = wp_t[(size_t)k * COUT + co];

    int ht = (h == 0) ? 0 : ((h == HH - 1) ? 2 : 1);
    float a_l = adj[(ht * 3 + 0) * COUT + co];
    float a_m = adj[(ht * 3 + 1) * COUT + co];
    float a_r = adj[(ht * 3 + 2) * COUT + co];

    __syncthreads();

    float* outp = out + ((size_t)n * COUT + co) * HW + h * WW;

    #pragma unroll 4
    for (int w_ = 0; w_ < WW; ++w_) {
        int p0 = 0, p1 = 0, p2 = 0;
        #pragma unroll
        for (int r = 0; r < 3; ++r) {
            #pragma unroll
            for (int c = 0; c < 3; ++c) {
                const uint4* xq = (const uint4*)&tile[r][w_ + c][0];
                uint4 xa = xq[0], xb4 = xq[1];
                const int kb = (r * 3 + c) * 8;
                int* acc = (r == 0) ? &p0 : (r == 1 ? &p1 : &p2);
                *acc += __popc(xa.x  ^ wreg[kb + 0]);
                *acc += __popc(xa.y  ^ wreg[kb + 1]);
                *acc += __popc(xa.z  ^ wreg[kb + 2]);
                *acc += __popc(xa.w  ^ wreg[kb + 3]);
                *acc += __popc(xb4.x ^ wreg[kb + 4]);
                *acc += __popc(xb4.y ^ wreg[kb + 5]);
                *acc += __popc(xb4.z ^ wreg[kb + 6]);
                *acc += __popc(xb4.w ^ wreg[kb + 7]);
            }
        }
        int pop = p0 + p1 + p2;
        float av = (w_ == 0) ? a_l : ((w_ == WW - 1) ? a_r : a_m);
        outp[w_] = (float)(2304 - 2 * pop) + av;
    }
}

extern "C" void kernel_launch(void* const* d_in, const int* in_sizes, int n_in,
                              void* d_out, int out_size, void* d_ws, size_t ws_size,
                              hipStream_t stream) {
    const float* x = (const float*)d_in[0];
    const float* w = (const float*)d_in[1];
    const float* b = (const float*)d_in[2];
    float* out = (float*)d_out;

    uint32_t* xp   = (uint32_t*)d_ws;
    uint32_t* wpck = (uint32_t*)((char*)d_ws + XP_BYTES);
    float*    adjp = (float*)((char*)d_ws + XP_BYTES + WP_BYTES);

    pack_x_kernel<<<NPIX / 64, 256, 0, stream>>>(x, xp);
    pack_w_kernel<<<COUT, 256, 0, stream>>>(w, b, wpck, adjp);

    bconv_kernel<<<NBATCH * HH, 256, 0, stream>>>(xp, wpck, adjp, out);
}

// Round 5
// 182.237 us; speedup vs baseline: 10.6777x; 10.6777x over previous
//
#include <hip/hip_runtime.h>
#include <hip/hip_bf16.h>
#include <stdint.h>

// BConv2d: out = conv2d(sign(x), sign(w), pad=1) + b
// N=32, Cin=256, H=W=56, Cout=256, K=3. fp32 in/out.
//
// dot(±1,±1) over 256-bit tap = 256 - 2*popcount(xor). OOB taps read as
// zeros (== all -1) via a zero-buffer redirect; false contribution removed
// by adj[bt][co] = bias[co] - sum_invalid(256 - 2*pop(w_tap)).
//
// R4 lesson: `int* acc = (r==0)?&p0:...` defeated SROA (runtime-selected
// address of locals) -> accumulators+arrays went to scratch (FETCH 4.3 GB).
// R5: lane=co, wreg[72] pinned in VGPRs, register sliding window (A/B/C
// column sets rotated by NAMING, all indices static), LDS-transposed output
// staging for coalesced stores. No address-taken locals anywhere.

#define NBATCH 32
#define CIN    256
#define COUT   256
#define HH     56
#define WW     56
#define HW     (HH*WW)          // 3136
#define NPIX   (NBATCH*HW)      // 100352

#define XP_BYTES  ((size_t)NPIX * 8 * 4)       // 3,211,264
#define WP_BYTES  ((size_t)COUT * 72 * 4)      // 73,728
#define ADJ_BYTES ((size_t)9 * COUT * 4)       // 9,216

// ---- pack x: wave handles 64 channels (2 words) for 64 pixels (lane=pixel)
__global__ __launch_bounds__(256) void pack_x_kernel(
    const float* __restrict__ x, uint32_t* __restrict__ xp)
{
    int lane = threadIdx.x & 63;
    int wv   = threadIdx.x >> 6;               // 0..3 -> channel group
    int pix  = blockIdx.x * 64 + lane;         // 1568 blocks * 64 == NPIX
    int n  = pix / HW;
    int hw = pix - n * HW;
    const float* xb = x + ((size_t)n * CIN + (size_t)wv * 64) * HW + hw;

    uint32_t w0 = 0, w1 = 0;
    #pragma unroll
    for (int j = 0; j < 32; ++j) {
        w0 |= (xb[(size_t)j * HW]        >= 0.0f ? 1u : 0u) << j;
        w1 |= (xb[(size_t)(j + 32) * HW] >= 0.0f ? 1u : 0u) << j;
    }
    *(uint2*)(xp + (size_t)pix * 8 + wv * 2) = make_uint2(w0, w1);
}

// ---- pack w (TRANSPOSED): wp_t[k*COUT + co], k = t*8 + wd; also zero zbuf
__global__ __launch_bounds__(256) void pack_w_kernel(
    const float* __restrict__ w, const float* __restrict__ bias,
    uint32_t* __restrict__ wp_t, float* __restrict__ adj,
    uint32_t* __restrict__ zbuf)
{
    int co   = blockIdx.x;
    int ci   = threadIdx.x;                    // 0..255
    int lane = ci & 63, wv = ci >> 6;
    if (co == 0 && ci < 8) zbuf[ci] = 0u;
    const float* wb = w + ((size_t)co * CIN + ci) * 9;

    float v[9];
    #pragma unroll
    for (int t = 0; t < 9; ++t) v[t] = wb[t];

    __shared__ int pops[4][9];
    __shared__ int popv[9];

    #pragma unroll
    for (int t = 0; t < 9; ++t) {
        unsigned long long m = __ballot(v[t] >= 0.0f);
        if (lane == 0) {
            wp_t[(size_t)(t * 8 + 2 * wv)     * COUT + co] = (uint32_t)m;
            wp_t[(size_t)(t * 8 + 2 * wv + 1) * COUT + co] = (uint32_t)(m >> 32);
            pops[wv][t] = (int)__popcll(m);
        }
    }
    __syncthreads();
    if (ci < 9) popv[ci] = pops[0][ci] + pops[1][ci] + pops[2][ci] + pops[3][ci];
    __syncthreads();
    if (ci < 9) {
        int bt = ci, ht = bt / 3, wt = bt % 3;
        float c = 0.0f;
        #pragma unroll
        for (int t = 0; t < 9; ++t) {
            int dh = t / 3, dw = t % 3;
            bool inv = (ht == 0 && dh == 0) || (ht == 2 && dh == 2) ||
                       (wt == 0 && dw == 0) || (wt == 2 && dw == 2);
            if (inv) c += (float)(CIN - 2 * popv[t]);
        }
        adj[bt * COUT + co] = bias[co] - c;
    }
}

// ---- conv: block=(n,h); lane=co (wave g -> co group g*64+lane)
#define TAP(ACC, ARR, r, dw) \
    ACC += __popc(ARR[r][0] ^ wreg[((r)*3+(dw))*8+0]); \
    ACC += __popc(ARR[r][1] ^ wreg[((r)*3+(dw))*8+1]); \
    ACC += __popc(ARR[r][2] ^ wreg[((r)*3+(dw))*8+2]); \
    ACC += __popc(ARR[r][3] ^ wreg[((r)*3+(dw))*8+3]); \
    ACC += __popc(ARR[r][4] ^ wreg[((r)*3+(dw))*8+4]); \
    ACC += __popc(ARR[r][5] ^ wreg[((r)*3+(dw))*8+5]); \
    ACC += __popc(ARR[r][6] ^ wreg[((r)*3+(dw))*8+6]); \
    ACC += __popc(ARR[r][7] ^ wreg[((r)*3+(dw))*8+7]);

#define COMP(L, M, R, wsel) { \
    int pA = 0, pB = 0, pC = 0, pD = 0; \
    TAP(pA, L, 0, 0) TAP(pB, M, 0, 1) TAP(pC, R, 0, 2) \
    TAP(pD, L, 1, 0) TAP(pA, M, 1, 1) TAP(pB, R, 1, 2) \
    TAP(pC, L, 2, 0) TAP(pD, M, 2, 1) TAP(pA, R, 2, 2) \
    int pop = pA + pB + pC + pD; \
    float av = ((wsel) == 0) ? a_l : (((wsel) == WW - 1) ? a_r : a_m); \
    ostage[co][(wsel)] = (float)(2304 - 2 * pop) + av; }

#define LOADCOL(D, col) { \
    const uint32_t* q0 = rp0 + (size_t)(col) * st0; \
    const uint32_t* q1 = rp1 + (size_t)(col) * 8;   \
    const uint32_t* q2 = rp2 + (size_t)(col) * st2; \
    uint4 u; \
    u = *(const uint4*)q0;       D[0][0]=u.x; D[0][1]=u.y; D[0][2]=u.z; D[0][3]=u.w; \
    u = *(const uint4*)(q0 + 4); D[0][4]=u.x; D[0][5]=u.y; D[0][6]=u.z; D[0][7]=u.w; \
    u = *(const uint4*)q1;       D[1][0]=u.x; D[1][1]=u.y; D[1][2]=u.z; D[1][3]=u.w; \
    u = *(const uint4*)(q1 + 4); D[1][4]=u.x; D[1][5]=u.y; D[1][6]=u.z; D[1][7]=u.w; \
    u = *(const uint4*)q2;       D[2][0]=u.x; D[2][1]=u.y; D[2][2]=u.z; D[2][3]=u.w; \
    u = *(const uint4*)(q2 + 4); D[2][4]=u.x; D[2][5]=u.y; D[2][6]=u.z; D[2][7]=u.w; }

__global__ __launch_bounds__(256, 2) void bconv_kernel(
    const uint32_t* __restrict__ xp, const uint32_t* __restrict__ wp_t,
    const float* __restrict__ adj, const uint32_t* __restrict__ zbuf,
    float* __restrict__ out)
{
    __shared__ float ostage[COUT][57];   // 58,368 B; stride 57 -> conflict-free

    int bx = blockIdx.x;                 // 0..1791
    int n  = bx / HH;
    int h  = bx - n * HH;
    int tid  = threadIdx.x;
    int lane = tid & 63;
    int wg   = tid >> 6;
    int co   = wg * 64 + lane;

    // pin this lane's co weights in VGPRs (coalesced, L2-resident)
    uint32_t wreg[72];
    #pragma unroll
    for (int k = 0; k < 72; ++k) wreg[k] = wp_t[(size_t)k * COUT + co];

    int ht = (h == 0) ? 0 : ((h == HH - 1) ? 2 : 1);
    float a_l = adj[(ht * 3 + 0) * COUT + co];
    float a_m = adj[(ht * 3 + 1) * COUT + co];
    float a_r = adj[(ht * 3 + 2) * COUT + co];

    // row pointers; invalid rows -> zbuf with stride 0 (branch-free inner loop)
    const uint32_t* base = xp + (size_t)n * HW * 8;
    const uint32_t* rp0; const uint32_t* rp2;
    const uint32_t* rp1 = base + (size_t)h * WW * 8;
    size_t st0, st2;
    if (h > 0)      { rp0 = base + (size_t)(h - 1) * WW * 8; st0 = 8; }
    else            { rp0 = zbuf; st0 = 0; }
    if (h < HH - 1) { rp2 = base + (size_t)(h + 1) * WW * 8; st2 = 8; }
    else            { rp2 = zbuf; st2 = 0; }

    // sliding window: A/B/C hold 3 columns x 3 rows x 8 words
    uint32_t A[3][8], B[3][8], C[3][8];
    #pragma unroll
    for (int r = 0; r < 3; ++r) {
        #pragma unroll
        for (int j = 0; j < 8; ++j) A[r][j] = 0u;   // col -1 = zeros
    }
    LOADCOL(B, 0)
    LOADCOL(C, 1)
    COMP(A, B, C, 0)

    for (int w_ = 1; w_ < 55; w_ += 3) {           // 18 iters: pixels 1..54
        LOADCOL(A, w_ + 1) COMP(B, C, A, w_)
        LOADCOL(B, w_ + 2) COMP(C, A, B, w_ + 1)
        LOADCOL(C, w_ + 3) COMP(A, B, C, w_ + 2)
    }
    #pragma unroll
    for (int r = 0; r < 3; ++r) {
        #pragma unroll
        for (int j = 0; j < 8; ++j) A[r][j] = 0u;   // col 56 = zeros
    }
    COMP(B, C, A, 55)

    __syncthreads();

    // coalesced flush: 3584 float4 per block, 14 per thread
    float* ob = out + (size_t)n * COUT * HW + (size_t)h * WW;
    #pragma unroll
    for (int k = 0; k < 14; ++k) {
        int e4  = k * 256 + tid;                   // 0..3583
        int co2 = e4 / 14;
        int q   = e4 - co2 * 14;
        float4 v;
        v.x = ostage[co2][4 * q + 0];
        v.y = ostage[co2][4 * q + 1];
        v.z = ostage[co2][4 * q + 2];
        v.w = ostage[co2][4 * q + 3];
        *(float4*)(ob + (size_t)co2 * HW + 4 * q) = v;
    }
}

extern "C" void kernel_launch(void* const* d_in, const int* in_sizes, int n_in,
                              void* d_out, int out_size, void* d_ws, size_t ws_size,
                              hipStream_t stream) {
    const float* x = (const float*)d_in[0];
    const float* w = (const float*)d_in[1];
    const float* b = (const float*)d_in[2];
    float* out = (float*)d_out;

    uint32_t* xp   = (uint32_t*)d_ws;
    uint32_t* wpck = (uint32_t*)((char*)d_ws + XP_BYTES);
    float*    adjp = (float*)((char*)d_ws + XP_BYTES + WP_BYTES);
    uint32_t* zbuf = (uint32_t*)((char*)d_ws + XP_BYTES + WP_BYTES + ADJ_BYTES);

    pack_x_kernel<<<NPIX / 64, 256, 0, stream>>>(x, xp);
    pack_w_kernel<<<COUT, 256, 0, stream>>>(w, b, wpck, adjp, zbuf);

    bconv_kernel<<<NBATCH * HH, 256, 0, stream>>>(xp, wpck, adjp, zbuf, out);
}